// Round 3
// baseline (2169.296 us; speedup 1.0000x reference)
//
#include <hip/hip_runtime.h>

#define DIMC 1024
#define SEQ  2048
#define NHEAD 16
#define BATCH 8

// ---------------------------------------------------------------- helpers
__device__ __forceinline__ void gll4(const float* g, float* l) {
  __builtin_amdgcn_global_load_lds(
      (const __attribute__((address_space(1))) void*)g,
      (__attribute__((address_space(3))) void*)l, 4, 0, 0);
}
__device__ __forceinline__ void gll16(const unsigned short* g, unsigned short* l) {
  __builtin_amdgcn_global_load_lds(
      (const __attribute__((address_space(1))) void*)g,
      (__attribute__((address_space(3))) void*)l, 16, 0, 0);
}

// waitcnt immediates (gfx9 encoding: vm[3:0]=b3:0, exp=b6:4, lgkm=b11:8, vm[5:4]=b15:14)
// 2-ahead ring math: per half-step FIFO = {coef store, k load, v load}; the
// slot-(t+2) v-load was issued 14 half-steps ago -> younger = 13*3 + 3 = 42.
#define WAIT_VM42   0x8F7A  // vmcnt<=42
#define WAIT_VM0    0x0F70  // vmcnt<=0

// fp32 <-> bf16 (RNE)
__device__ __forceinline__ unsigned short f2bf(float f) {
  unsigned u = __float_as_uint(f);
  return (unsigned short)((u + 0x7fffu + ((u >> 16) & 1u)) >> 16);
}
__device__ __forceinline__ float bf2f(unsigned short h) {
  return __uint_as_float(((unsigned)h) << 16);
}

typedef __attribute__((ext_vector_type(8))) short  bf16x8;
typedef __attribute__((ext_vector_type(4))) float  floatx4;

// sum over 8 contiguous (8-aligned) lanes, pure DPP: ^1, ^2, then half-row mirror
__device__ __forceinline__ float oct_sum(float x) {
  int t1 = __builtin_amdgcn_update_dpp(0, __float_as_int(x), 0xB1, 0xF, 0xF, true);   // quad_perm(1,0,3,2)
  float x1 = x + __int_as_float(t1);
  int t2 = __builtin_amdgcn_update_dpp(0, __float_as_int(x1), 0x4E, 0xF, 0xF, true);  // quad_perm(2,3,0,1)
  float x2 = x1 + __int_as_float(t2);
  int t3 = __builtin_amdgcn_update_dpp(0, __float_as_int(x2), 0x141, 0xF, 0xF, true); // row_half_mirror
  return x2 + __int_as_float(t3);
}

// ---------------------------------------------------------------- split fp32 -> bf16 hi/lo
__global__ __launch_bounds__(256)
void cvt_split(const float* __restrict__ in, unsigned short* __restrict__ hi,
               unsigned short* __restrict__ lo, int n4)
{
  int i = blockIdx.x * 256 + threadIdx.x;
  if (i >= n4) return;
  float4 f = ((const float4*)in)[i];
  unsigned short h0 = f2bf(f.x), h1 = f2bf(f.y), h2 = f2bf(f.z), h3 = f2bf(f.w);
  unsigned short l0 = f2bf(f.x - bf2f(h0)), l1 = f2bf(f.y - bf2f(h1));
  unsigned short l2 = f2bf(f.z - bf2f(h2)), l3 = f2bf(f.w - bf2f(h3));
  ushort4 H; H.x = h0; H.y = h1; H.z = h2; H.w = h3;
  ushort4 L; L.x = l0; L.y = l1; L.z = l2; L.w = l3;
  ((ushort4*)hi)[i] = H;
  ((ushort4*)lo)[i] = L;
}

// ---------------------------------------------------------------- pack Wa/Wb into padded 128x1024
__global__ void pack_ab_kernel(const float* __restrict__ Wa, const float* __restrict__ ba,
                               const float* __restrict__ Wb, const float* __restrict__ bb,
                               float* __restrict__ Wab, float* __restrict__ bab)
{
  int i = blockIdx.x * 256 + threadIdx.x;
  if (i < 128 * 1024) {
    int row = i >> 10, col = i & 1023;
    float v = 0.0f;
    if (row < 16) v = Wa[(row << 10) + col];
    else if (row < 32) v = Wb[((row - 16) << 10) + col];
    Wab[i] = v;
  } else {
    int j = i - 128 * 1024;
    if (j < 128) {
      float v = 0.0f;
      if (j < 16) v = ba[j];
      else if (j < 32) v = bb[j - 16];
      bab[j] = v;
    }
  }
}

// ---------------------------------------------------------------- split-bf16 MFMA GEMM
__global__ __launch_bounds__(256, 2)
void gemm_bf16x3(const unsigned short* __restrict__ Ah, const unsigned short* __restrict__ Al,
                 const unsigned short* __restrict__ Bh, const unsigned short* __restrict__ Bl,
                 const float* __restrict__ bias, float* __restrict__ C,
                 int K, int ldc, int nvalid, int act)
{
  __shared__ unsigned short sAh[4096], sAl[4096], sBh[4096], sBl[4096];
  const int tid  = threadIdx.x;
  const int lane = tid & 63;
  const int w    = tid >> 6;

  const int crow = tid >> 2;
  const int kel  = (tid & 3) << 3;
  const unsigned short* pAh0 = Ah + (size_t)(blockIdx.x * 128 + crow) * K + kel;
  const unsigned short* pAh1 = Ah + (size_t)(blockIdx.x * 128 + 64 + crow) * K + kel;
  const unsigned short* pAl0 = Al + (size_t)(blockIdx.x * 128 + crow) * K + kel;
  const unsigned short* pAl1 = Al + (size_t)(blockIdx.x * 128 + 64 + crow) * K + kel;
  const unsigned short* pBh0 = Bh + (size_t)(blockIdx.y * 128 + crow) * K + kel;
  const unsigned short* pBh1 = Bh + (size_t)(blockIdx.y * 128 + 64 + crow) * K + kel;
  const unsigned short* pBl0 = Bl + (size_t)(blockIdx.y * 128 + crow) * K + kel;
  const unsigned short* pBl1 = Bl + (size_t)(blockIdx.y * 128 + 64 + crow) * K + kel;
  const int wb = (tid & 192) * 8;

  floatx4 acc[16];
  #pragma unroll
  for (int i = 0; i < 16; ++i) acc[i] = (floatx4){0.f, 0.f, 0.f, 0.f};

  const int mq = (w & 1) << 6;
  const int nq = (w >> 1) << 6;
  const int fr = lane & 15;
  const int fk = (lane >> 4) << 3;

  for (int kt = 0; kt < K; kt += 32) {
    __syncthreads();
    gll16(pAh0, sAh + wb); gll16(pAh1, sAh + 2048 + wb);
    gll16(pAl0, sAl + wb); gll16(pAl1, sAl + 2048 + wb);
    gll16(pBh0, sBh + wb); gll16(pBh1, sBh + 2048 + wb);
    gll16(pBl0, sBl + wb); gll16(pBl1, sBl + 2048 + wb);
    pAh0 += 32; pAh1 += 32; pAl0 += 32; pAl1 += 32;
    pBh0 += 32; pBh1 += 32; pBl0 += 32; pBl1 += 32;
    __syncthreads();

    bf16x8 ah[4], al[4], bh[4], bl[4];
    #pragma unroll
    for (int mi = 0; mi < 4; ++mi) {
      int off = (mq + mi * 16 + fr) * 32 + fk;
      ah[mi] = *(const bf16x8*)&sAh[off];
      al[mi] = *(const bf16x8*)&sAl[off];
    }
    #pragma unroll
    for (int ni = 0; ni < 4; ++ni) {
      int off = (nq + ni * 16 + fr) * 32 + fk;
      bh[ni] = *(const bf16x8*)&sBh[off];
      bl[ni] = *(const bf16x8*)&sBl[off];
    }
    #pragma unroll
    for (int mi = 0; mi < 4; ++mi)
      #pragma unroll
      for (int ni = 0; ni < 4; ++ni) {
        floatx4 c = acc[mi * 4 + ni];
        c = __builtin_amdgcn_mfma_f32_16x16x32_bf16(ah[mi], bh[ni], c, 0, 0, 0);
        c = __builtin_amdgcn_mfma_f32_16x16x32_bf16(ah[mi], bl[ni], c, 0, 0, 0);
        c = __builtin_amdgcn_mfma_f32_16x16x32_bf16(al[mi], bh[ni], c, 0, 0, 0);
        acc[mi * 4 + ni] = c;
      }
  }

  const int mbase = blockIdx.x * 128 + mq + ((lane >> 4) << 2);
  const int nbase = blockIdx.y * 128 + nq + (lane & 15);
  #pragma unroll
  for (int ni = 0; ni < 4; ++ni) {
    int n = nbase + ni * 16;
    if (n < nvalid) {
      float bs = bias[n];
      #pragma unroll
      for (int mi = 0; mi < 4; ++mi) {
        #pragma unroll
        for (int r = 0; r < 4; ++r) {
          int m = mbase + mi * 16 + r;
          float val = acc[mi * 4 + ni][r] + bs;
          if (act == 1)      val = val * (1.0f / (1.0f + __expf(-val)));
          else if (act == 2) val = 1.0f / (1.0f + __expf(-val));
          C[(size_t)m * ldc + n] = val;
        }
      }
    }
  }
}

// ---------------------------------------------------------------- depthwise conv(K=4,pad2) + silu + optional l2norm
__global__ __launch_bounds__(256)
void conv_kernel(const float* __restrict__ pre, const float* __restrict__ w,
                 float* __restrict__ out, int do_norm)
{
  __shared__ float red[4];
  const int bt  = blockIdx.x;
  const int t   = bt & (SEQ - 1);
  const int tid = threadIdx.x;
  const int c   = tid << 2;
  const float* rowp = pre + (size_t)bt * DIMC + c;
  const float4 z = make_float4(0.f, 0.f, 0.f, 0.f);
  float4 xm2 = (t >= 2)      ? *(const float4*)(rowp - 2 * DIMC) : z;
  float4 xm1 = (t >= 1)      ? *(const float4*)(rowp - DIMC)     : z;
  float4 x0  =                 *(const float4*)(rowp);
  float4 xp1 = (t + 1 < SEQ) ? *(const float4*)(rowp + DIMC)     : z;
  const float4 w0 = *(const float4*)(w + (size_t)(c + 0) * 4);
  const float4 w1 = *(const float4*)(w + (size_t)(c + 1) * 4);
  const float4 w2 = *(const float4*)(w + (size_t)(c + 2) * 4);
  const float4 w3 = *(const float4*)(w + (size_t)(c + 3) * 4);
  float y0 = xm2.x * w0.x + xm1.x * w0.y + x0.x * w0.z + xp1.x * w0.w;
  float y1 = xm2.y * w1.x + xm1.y * w1.y + x0.y * w1.z + xp1.y * w1.w;
  float y2 = xm2.z * w2.x + xm1.z * w2.y + x0.z * w2.z + xp1.z * w2.w;
  float y3 = xm2.w * w3.x + xm1.w * w3.y + x0.w * w3.z + xp1.w * w3.w;
  y0 = y0 * (1.0f / (1.0f + __expf(-y0)));
  y1 = y1 * (1.0f / (1.0f + __expf(-y1)));
  y2 = y2 * (1.0f / (1.0f + __expf(-y2)));
  y3 = y3 * (1.0f / (1.0f + __expf(-y3)));
  if (do_norm) {
    float ss = y0*y0 + y1*y1 + y2*y2 + y3*y3;
    #pragma unroll
    for (int off = 32; off >= 1; off >>= 1) ss += __shfl_xor(ss, off);
    if ((tid & 63) == 0) red[tid >> 6] = ss;
    __syncthreads();
    float tot = red[0] + red[1] + red[2] + red[3];
    float rn = 1.0f / (sqrtf(tot) + 1e-6f);
    y0 *= rn; y1 *= rn; y2 *= rn; y3 *= rn;
  }
  *(float4*)(out + (size_t)bt * DIMC + c) = make_float4(y0, y1, y2, y3);
}

// ---------------------------------------------------------------- gated delta scan, pass 1 (serial)
// S(t) = a*S(t-1) + coef_t k_t^T, coef_t = bg*v - a*bg*(S k).
// Pair-unrolled with two register sets; each set's LDS reads are issued a FULL
// step before use (2-ahead), hiding ~120cy ds_read latency under the other step.
#define PD 16
__global__ __launch_bounds__(64)
void scan2_kernel(const float* __restrict__ k, const float* __restrict__ v,
                  const float* __restrict__ ab, float* __restrict__ Cf,
                  float* __restrict__ SC)
{
  __shared__ float ring[PD][2][64];   // [slot][k|v][64]
  __shared__ float aS[SEQ];
  __shared__ float bSh[SEQ];
  const int blk = blockIdx.x;
  const int bh  = blk >> 3;           // b*16+h
  const int dg  = blk & 7;            // 8-row group
  const int b   = bh >> 4, h = bh & 15;
  const int tid = threadIdx.x;        // 0..63, one wave
  const int eh  = tid & 7;            // e-octant
  const int d   = dg * 8 + (tid >> 3);
  const int e0  = eh * 8;

  const float* abbase = ab + (size_t)b * SEQ * 32 + h;
  for (int i = tid; i < SEQ; i += 64) {
    aS[i]  = abbase[(size_t)i * 32];
    bSh[i] = abbase[(size_t)i * 32 + 16];
  }

  const size_t base = (size_t)b * SEQ * DIMC + h * 64;
  const float* kp = k + base + tid;
  const float* vp = v + base + tid;

  // zero checkpoint for chunk 0
  {
    float4 z4 = make_float4(0.f, 0.f, 0.f, 0.f);
    float4* dst0 = (float4*)&SC[(((size_t)bh * 32) * 64 + d) * 64 + e0];
    dst0[0] = z4; dst0[1] = z4;
  }

  #pragma unroll
  for (int pt = 0; pt < PD; ++pt) {
    gll4(kp + (size_t)pt * DIMC, &ring[pt][0][0]);
    gll4(vp + (size_t)pt * DIMC, &ring[pt][1][0]);
  }
  __builtin_amdgcn_s_waitcnt(WAIT_VM0);   // drain prologue
  asm volatile("" ::: "memory");

  float S[8];
  #pragma unroll
  for (int j = 0; j < 8; ++j) S[j] = 0.f;

  float* cfp = Cf + (size_t)bh * SEQ * 64 + d;

  // preload set A (step 0) and set B (step 1)
  float4 kaA = *(const float4*)&ring[0][0][e0];
  float4 kbA = *(const float4*)&ring[0][0][e0 + 4];
  float  vdA = ring[0][1][d];
  float  aA  = aS[0];
  float  bgA = bSh[0];
  float4 kaB = *(const float4*)&ring[1][0][e0];
  float4 kbB = *(const float4*)&ring[1][0][e0 + 4];
  float  vdB = ring[1][1][d];
  float  aB  = aS[1];
  float  bgB = bSh[1];

  for (int t = 0; t < SEQ; t += 2) {
    // ================= step t (set A) =================
    {
      float p0 = fmaf(S[0], kaA.x, S[4] * kbA.x);
      float p1 = fmaf(S[1], kaA.y, S[5] * kbA.y);
      float p2 = fmaf(S[2], kaA.z, S[6] * kbA.z);
      float p3 = fmaf(S[3], kaA.w, S[7] * kbA.w);
      float sk = oct_sum((p0 + p1) + (p2 + p3));
      const float abg = aA * bgA;                 // off-chain, regs 1 step old
      const float bv  = bgA * vdA;
      const float coef = fmaf(-abg, sk, bv);
      if (eh == 0) cfp[(size_t)t * 64] = coef;

      S[0] = fmaf(aA, S[0], coef * kaA.x);
      S[1] = fmaf(aA, S[1], coef * kaA.y);
      S[2] = fmaf(aA, S[2], coef * kaA.z);
      S[3] = fmaf(aA, S[3], coef * kaA.w);
      S[4] = fmaf(aA, S[4], coef * kbA.x);
      S[5] = fmaf(aA, S[5], coef * kbA.y);
      S[6] = fmaf(aA, S[6], coef * kbA.z);
      S[7] = fmaf(aA, S[7], coef * kbA.w);

      asm volatile("" ::: "memory");
      if (t < SEQ - PD) {
        const int slot = t & (PD - 1);          // for step t+PD
        gll4(kp + (size_t)(t + PD) * DIMC, &ring[slot][0][0]);
        gll4(vp + (size_t)(t + PD) * DIMC, &ring[slot][1][0]);
        asm volatile("" ::: "memory");
        __builtin_amdgcn_s_waitcnt(WAIT_VM42);  // slot (t+2) resident
      } else {
        asm volatile("" ::: "memory");
        __builtin_amdgcn_s_waitcnt(WAIT_VM0);
      }
      asm volatile("" ::: "memory");

      // reads for step t+2 -> set A (consumed a full step from now)
      const int sl = (t + 2) & (PD - 1);
      const int tn = (t + 2) & (SEQ - 1);
      kaA = *(const float4*)&ring[sl][0][e0];
      kbA = *(const float4*)&ring[sl][0][e0 + 4];
      vdA = ring[sl][1][d];
      aA  = aS[tn];
      bgA = bSh[tn];
    }

    // ================= step t+1 (set B) =================
    {
      float p0 = fmaf(S[0], kaB.x, S[4] * kbB.x);
      float p1 = fmaf(S[1], kaB.y, S[5] * kbB.y);
      float p2 = fmaf(S[2], kaB.z, S[6] * kbB.z);
      float p3 = fmaf(S[3], kaB.w, S[7] * kbB.w);
      float sk = oct_sum((p0 + p1) + (p2 + p3));
      const float abg = aB * bgB;
      const float bv  = bgB * vdB;
      const float coef = fmaf(-abg, sk, bv);
      if (eh == 0) cfp[(size_t)(t + 1) * 64] = coef;

      S[0] = fmaf(aB, S[0], coef * kaB.x);
      S[1] = fmaf(aB, S[1], coef * kaB.y);
      S[2] = fmaf(aB, S[2], coef * kaB.z);
      S[3] = fmaf(aB, S[3], coef * kaB.w);
      S[4] = fmaf(aB, S[4], coef * kbB.x);
      S[5] = fmaf(aB, S[5], coef * kbB.y);
      S[6] = fmaf(aB, S[6], coef * kbB.z);
      S[7] = fmaf(aB, S[7], coef * kbB.w);

      if (((t + 2) & 63) == 0 && (t + 2) < SEQ) {  // checkpoint entering chunk (t+2)>>6
        float4* dst = (float4*)&SC[(((size_t)bh * 32 + ((t + 2) >> 6)) * 64 + d) * 64 + e0];
        dst[0] = make_float4(S[0], S[1], S[2], S[3]);
        dst[1] = make_float4(S[4], S[5], S[6], S[7]);
      }

      asm volatile("" ::: "memory");
      if (t + 1 < SEQ - PD) {
        const int slot = (t + 1) & (PD - 1);    // for step t+1+PD
        gll4(kp + (size_t)(t + 1 + PD) * DIMC, &ring[slot][0][0]);
        gll4(vp + (size_t)(t + 1 + PD) * DIMC, &ring[slot][1][0]);
        asm volatile("" ::: "memory");
        __builtin_amdgcn_s_waitcnt(WAIT_VM42);  // slot (t+3) resident
      } else {
        asm volatile("" ::: "memory");
        __builtin_amdgcn_s_waitcnt(WAIT_VM0);
      }
      asm volatile("" ::: "memory");

      // reads for step t+3 -> set B
      const int sl = (t + 3) & (PD - 1);
      const int tn = (t + 3) & (SEQ - 1);
      kaB = *(const float4*)&ring[sl][0][e0];
      kbB = *(const float4*)&ring[sl][0][e0 + 4];
      vdB = ring[sl][1][d];
      aB  = aS[tn];
      bgB = bSh[tn];
    }
  }
}

// ---------------------------------------------------------------- gated delta scan, pass 2 (parallel)
__global__ __launch_bounds__(256)
void outp_kernel(const float* __restrict__ q, const float* __restrict__ k,
                 const float* __restrict__ Cf, const float* __restrict__ SC,
                 const float* __restrict__ ab, float* __restrict__ O)
{
  __shared__ float QsT[64 * 64];  // [d][t]
  __shared__ float CP [64 * 64];  // CsT [d][s], then reused as PT [s][t]
  __shared__ float Ks [64 * 64];  // [s][e]
  __shared__ float Zs [64 * 64];  // [d][e]
  __shared__ float av[64], Gv[64], rGv[64];

  const int c   = blockIdx.x;
  const int bh  = blockIdx.y;
  const int b   = bh >> 4, h = bh & 15;
  const int cs  = c << 6;
  const int tid = threadIdx.x;
  const int tl  = tid & 63, th = tid >> 6;

  {
    const float* qr = q  + ((size_t)(b * SEQ + cs + tl)) * DIMC + h * 64 + th * 16;
    const float* cr = Cf + ((size_t)bh * SEQ + cs + tl) * 64 + th * 16;
    #pragma unroll
    for (int u = 0; u < 4; ++u) {
      float4 qv = *(const float4*)(qr + u * 4);
      float4 cv = *(const float4*)(cr + u * 4);
      int dd = th * 16 + u * 4;
      QsT[(dd+0)*64 + tl] = qv.x; QsT[(dd+1)*64 + tl] = qv.y;
      QsT[(dd+2)*64 + tl] = qv.z; QsT[(dd+3)*64 + tl] = qv.w;
      CP [(dd+0)*64 + tl] = cv.x; CP [(dd+1)*64 + tl] = cv.y;
      CP [(dd+2)*64 + tl] = cv.z; CP [(dd+3)*64 + tl] = cv.w;
    }
    const float* kr = k  + ((size_t)(b * SEQ + cs + tl)) * DIMC + h * 64 + th * 16;
    const float* zr = SC + (((size_t)bh * 32 + c) * 64 + tl) * 64 + th * 16;
    #pragma unroll
    for (int u = 0; u < 4; ++u) {
      *(float4*)&Ks[tl * 64 + th * 16 + u * 4] = *(const float4*)(kr + u * 4);
      *(float4*)&Zs[tl * 64 + th * 16 + u * 4] = *(const float4*)(zr + u * 4);
    }
    if (tid < 64) av[tid] = ab[((size_t)(b * SEQ + cs + tid)) * 32 + h];
  }
  __syncthreads();
  if (tid == 0) {
    float g = 1.f;
    for (int t = 0; t < 64; ++t) { g *= av[t]; Gv[t] = fmaxf(g, 1e-37f); }
  }
  __syncthreads();
  if (tid < 64) rGv[tid] = 1.0f / Gv[tid];
  __syncthreads();

  const int tq = (tid >> 4) << 2;         // 0,4,...,60
  const int s0 = (tid & 15) << 2;

  float p[4][4] = {{0.f}};
  #pragma unroll 4
  for (int dd = 0; dd < 64; ++dd) {
    const float4 qv = *(const float4*)&QsT[dd * 64 + tq];
    const float4 cv = *(const float4*)&CP [dd * 64 + s0];
    const float qa[4] = {qv.x, qv.y, qv.z, qv.w};
    const float ca[4] = {cv.x, cv.y, cv.z, cv.w};
    #pragma unroll
    for (int i = 0; i < 4; ++i)
      #pragma unroll
      for (int j = 0; j < 4; ++j)
        p[i][j] = fmaf(qa[i], ca[j], p[i][j]);
  }
  __syncthreads();

  #pragma unroll
  for (int i = 0; i < 4; ++i) {
    const float gt = Gv[tq + i];
    #pragma unroll
    for (int j = 0; j < 4; ++j) {
      float vsc = (s0 + j <= tq + i) ? p[i][j] * gt * rGv[s0 + j] : 0.f;
      CP[(s0 + j) * 64 + (tq + i)] = vsc;
    }
  }
  __syncthreads();

  const int e0 = s0;
  float o[4][4] = {{0.f}};
  #pragma unroll 4
  for (int ss = 0; ss < 64; ++ss) {
    const float4 pv = *(const float4*)&CP[ss * 64 + tq];
    const float4 kv = *(const float4*)&Ks[ss * 64 + e0];
    const float pa[4] = {pv.x, pv.y, pv.z, pv.w};
    const float ka[4] = {kv.x, kv.y, kv.z, kv.w};
    #pragma unroll
    for (int i = 0; i < 4; ++i)
      #pragma unroll
      for (int j = 0; j < 4; ++j)
        o[i][j] = fmaf(pa[i], ka[j], o[i][j]);
  }
  float zt[4][4] = {{0.f}};
  #pragma unroll 4
  for (int dd = 0; dd < 64; ++dd) {
    const float4 qv = *(const float4*)&QsT[dd * 64 + tq];
    const float4 zv = *(const float4*)&Zs[dd * 64 + e0];
    const float qa[4] = {qv.x, qv.y, qv.z, qv.w};
    const float za[4] = {zv.x, zv.y, zv.z, zv.w};
    #pragma unroll
    for (int i = 0; i < 4; ++i)
      #pragma unroll
      for (int j = 0; j < 4; ++j)
        zt[i][j] = fmaf(qa[i], za[j], zt[i][j]);
  }
  #pragma unroll
  for (int i = 0; i < 4; ++i) {
    const float gt = Gv[tq + i];
    float4 res;
    res.x = fmaf(gt, zt[i][0], o[i][0]);
    res.y = fmaf(gt, zt[i][1], o[i][1]);
    res.z = fmaf(gt, zt[i][2], o[i][2]);
    res.w = fmaf(gt, zt[i][3], o[i][3]);
    *(float4*)(O + ((size_t)(b * SEQ + cs + tq + i)) * DIMC + h * 64 + e0) = res;
  }
}

// ---------------------------------------------------------------- host
extern "C" void kernel_launch(void* const* d_in, const int* in_sizes, int n_in,
                              void* d_out, int out_size, void* d_ws, size_t ws_size,
                              hipStream_t stream)
{
  const float* x  = (const float*)d_in[0];
  const float* Wq = (const float*)d_in[1];
  const float* bq = (const float*)d_in[2];
  const float* Wk = (const float*)d_in[3];
  const float* bk = (const float*)d_in[4];
  const float* Wv = (const float*)d_in[5];
  const float* bv = (const float*)d_in[6];
  const float* Wa = (const float*)d_in[7];
  const float* ba = (const float*)d_in[8];
  const float* Wb = (const float*)d_in[9];
  const float* bb = (const float*)d_in[10];
  const float* cq = (const float*)d_in[11];
  const float* ck = (const float*)d_in[12];
  const float* cv = (const float*)d_in[13];
  const float* Wo = (const float*)d_in[14];
  const float* bo = (const float*)d_in[15];
  float* out = (float*)d_out;
  float* ws  = (float*)d_ws;

  const size_t per_b = (size_t)SEQ * DIMC;     // 2,097,152
  const size_t wsz   = (size_t)DIMC * DIMC;    // 1,048,576

  int bc = BATCH;
  while (bc > 1) {
    size_t fl = 4 * (size_t)bc * per_b + (size_t)bc * SEQ * 32 + 128 * 1024 + 128;
    size_t us = 2 * (size_t)bc * per_b + 8 * wsz + 2 * 128 * 1024;
    if (fl * 4 + us * 2 <= ws_size) break;
    bc >>= 1;
  }

  float* P   = ws;
  float* qb  = P  + (size_t)bc * per_b;
  float* kb  = qb + (size_t)bc * per_b;
  float* vb  = kb + (size_t)bc * per_b;
  float* abb = vb + (size_t)bc * per_b;
  float* Wab = abb + (size_t)bc * SEQ * 32;
  float* bab = Wab + 128 * 1024;
  unsigned short* xh   = (unsigned short*)(bab + 128);
  unsigned short* xl   = xh  + (size_t)bc * per_b;
  unsigned short* wqh  = xl  + (size_t)bc * per_b;
  unsigned short* wql  = wqh + wsz;
  unsigned short* wkh  = wql + wsz;
  unsigned short* wkl  = wkh + wsz;
  unsigned short* wvh  = wkl + wsz;
  unsigned short* wvl  = wvh + wsz;
  unsigned short* woh  = wvl + wsz;
  unsigned short* wol  = woh + wsz;
  unsigned short* wabh = wol + wsz;
  unsigned short* wabl = wabh + 128 * 1024;

  float* Cf  = (float*)xh;
  float* SCp = P;

  pack_ab_kernel<<<513, 256, 0, stream>>>(Wa, ba, Wb, bb, Wab, bab);
  cvt_split<<<(int)(wsz / 4 + 255) / 256, 256, 0, stream>>>(Wq, wqh, wql, (int)(wsz / 4));
  cvt_split<<<(int)(wsz / 4 + 255) / 256, 256, 0, stream>>>(Wk, wkh, wkl, (int)(wsz / 4));
  cvt_split<<<(int)(wsz / 4 + 255) / 256, 256, 0, stream>>>(Wv, wvh, wvl, (int)(wsz / 4));
  cvt_split<<<(int)(wsz / 4 + 255) / 256, 256, 0, stream>>>(Wo, woh, wol, (int)(wsz / 4));
  cvt_split<<<(128 * 1024 / 4 + 255) / 256, 256, 0, stream>>>(Wab, wabh, wabl, 128 * 1024 / 4);

  for (int b0 = 0; b0 < BATCH; b0 += bc) {
    const float* xb = x + (size_t)b0 * per_b;
    const int M = bc * SEQ;
    const int n4 = (int)((size_t)bc * per_b / 4);
    dim3 gg(M / 128, DIMC / 128);
    dim3 gab(M / 128, 1);

    cvt_split<<<(n4 + 255) / 256, 256, 0, stream>>>(xb, xh, xl, n4);

    gemm_bf16x3<<<gg, 256, 0, stream>>>(xh, xl, wqh, wql, bq, P, DIMC, DIMC, DIMC, 1);
    conv_kernel<<<dim3(M), 256, 0, stream>>>(P, cq, qb, 1);
    gemm_bf16x3<<<gg, 256, 0, stream>>>(xh, xl, wkh, wkl, bk, P, DIMC, DIMC, DIMC, 1);
    conv_kernel<<<dim3(M), 256, 0, stream>>>(P, ck, kb, 1);
    gemm_bf16x3<<<gg, 256, 0, stream>>>(xh, xl, wvh, wvl, bv, P, DIMC, DIMC, DIMC, 1);
    conv_kernel<<<dim3(M), 256, 0, stream>>>(P, cv, vb, 0);
    gemm_bf16x3<<<gab, 256, 0, stream>>>(xh, xl, wabh, wabl, bab, abb, DIMC, 32, 32, 2);
    scan2_kernel<<<dim3(bc * NHEAD * 8), 64, 0, stream>>>(kb, vb, abb, Cf, SCp);
    outp_kernel<<<dim3(SEQ / 64, bc * NHEAD), 256, 0, stream>>>(qb, kb, Cf, SCp, abb, vb);
    cvt_split<<<(n4 + 255) / 256, 256, 0, stream>>>(vb, xh, xl, n4);
    gemm_bf16x3<<<gg, 256, 0, stream>>>(xh, xl, woh, wol, bo, out + (size_t)b0 * per_b, DIMC, DIMC, DIMC, 0);
  }
}

// Round 4
// 1619.932 us; speedup vs baseline: 1.3391x; 1.3391x over previous
//
#include <hip/hip_runtime.h>

#define DIMC 1024
#define SEQ  2048
#define NHEAD 16
#define BATCH 8

// ---------------------------------------------------------------- helpers
__device__ __forceinline__ void gll4(const float* g, float* l) {
  __builtin_amdgcn_global_load_lds(
      (const __attribute__((address_space(1))) void*)g,
      (__attribute__((address_space(3))) void*)l, 4, 0, 0);
}
__device__ __forceinline__ void gll16(const unsigned short* g, unsigned short* l) {
  __builtin_amdgcn_global_load_lds(
      (const __attribute__((address_space(1))) void*)g,
      (__attribute__((address_space(3))) void*)l, 16, 0, 0);
}

// waitcnt immediates (gfx9 encoding: vm[3:0]=b3:0, exp=b6:4, lgkm=b11:8, vm[5:4]=b15:14)
// pair-granularity ring: per pair FIFO = {2 coef stores, 2 k loads, 2 v loads} = 6.
// ring = PD steps = 8 pairs; entries younger than pair(t+2)'s loads = 7*6 = 42.
#define WAIT_VM42   0x8F7A  // vmcnt<=42
#define WAIT_VM0    0x0F70  // vmcnt<=0

// fp32 <-> bf16 (RNE)
__device__ __forceinline__ unsigned short f2bf(float f) {
  unsigned u = __float_as_uint(f);
  return (unsigned short)((u + 0x7fffu + ((u >> 16) & 1u)) >> 16);
}
__device__ __forceinline__ float bf2f(unsigned short h) {
  return __uint_as_float(((unsigned)h) << 16);
}

typedef __attribute__((ext_vector_type(8))) short  bf16x8;
typedef __attribute__((ext_vector_type(4))) float  floatx4;

// sum over 8 contiguous (8-aligned) lanes, pure DPP: ^1, ^2, then half-row mirror
__device__ __forceinline__ float oct_sum(float x) {
  int t1 = __builtin_amdgcn_update_dpp(0, __float_as_int(x), 0xB1, 0xF, 0xF, true);   // quad_perm(1,0,3,2)
  float x1 = x + __int_as_float(t1);
  int t2 = __builtin_amdgcn_update_dpp(0, __float_as_int(x1), 0x4E, 0xF, 0xF, true);  // quad_perm(2,3,0,1)
  float x2 = x1 + __int_as_float(t2);
  int t3 = __builtin_amdgcn_update_dpp(0, __float_as_int(x2), 0x141, 0xF, 0xF, true); // row_half_mirror
  return x2 + __int_as_float(t3);
}

// ---------------------------------------------------------------- split fp32 -> bf16 hi/lo
__global__ __launch_bounds__(256)
void cvt_split(const float* __restrict__ in, unsigned short* __restrict__ hi,
               unsigned short* __restrict__ lo, int n4)
{
  int i = blockIdx.x * 256 + threadIdx.x;
  if (i >= n4) return;
  float4 f = ((const float4*)in)[i];
  unsigned short h0 = f2bf(f.x), h1 = f2bf(f.y), h2 = f2bf(f.z), h3 = f2bf(f.w);
  unsigned short l0 = f2bf(f.x - bf2f(h0)), l1 = f2bf(f.y - bf2f(h1));
  unsigned short l2 = f2bf(f.z - bf2f(h2)), l3 = f2bf(f.w - bf2f(h3));
  ushort4 H; H.x = h0; H.y = h1; H.z = h2; H.w = h3;
  ushort4 L; L.x = l0; L.y = l1; L.z = l2; L.w = l3;
  ((ushort4*)hi)[i] = H;
  ((ushort4*)lo)[i] = L;
}

// ---------------------------------------------------------------- pack Wa/Wb into padded 128x1024
__global__ void pack_ab_kernel(const float* __restrict__ Wa, const float* __restrict__ ba,
                               const float* __restrict__ Wb, const float* __restrict__ bb,
                               float* __restrict__ Wab, float* __restrict__ bab)
{
  int i = blockIdx.x * 256 + threadIdx.x;
  if (i < 128 * 1024) {
    int row = i >> 10, col = i & 1023;
    float v = 0.0f;
    if (row < 16) v = Wa[(row << 10) + col];
    else if (row < 32) v = Wb[((row - 16) << 10) + col];
    Wab[i] = v;
  } else {
    int j = i - 128 * 1024;
    if (j < 128) {
      float v = 0.0f;
      if (j < 16) v = ba[j];
      else if (j < 32) v = bb[j - 16];
      bab[j] = v;
    }
  }
}

// ---------------------------------------------------------------- split-bf16 MFMA GEMM
__global__ __launch_bounds__(256, 2)
void gemm_bf16x3(const unsigned short* __restrict__ Ah, const unsigned short* __restrict__ Al,
                 const unsigned short* __restrict__ Bh, const unsigned short* __restrict__ Bl,
                 const float* __restrict__ bias, float* __restrict__ C,
                 int K, int ldc, int nvalid, int act)
{
  __shared__ unsigned short sAh[4096], sAl[4096], sBh[4096], sBl[4096];
  const int tid  = threadIdx.x;
  const int lane = tid & 63;
  const int w    = tid >> 6;

  const int crow = tid >> 2;
  const int kel  = (tid & 3) << 3;
  const unsigned short* pAh0 = Ah + (size_t)(blockIdx.x * 128 + crow) * K + kel;
  const unsigned short* pAh1 = Ah + (size_t)(blockIdx.x * 128 + 64 + crow) * K + kel;
  const unsigned short* pAl0 = Al + (size_t)(blockIdx.x * 128 + crow) * K + kel;
  const unsigned short* pAl1 = Al + (size_t)(blockIdx.x * 128 + 64 + crow) * K + kel;
  const unsigned short* pBh0 = Bh + (size_t)(blockIdx.y * 128 + crow) * K + kel;
  const unsigned short* pBh1 = Bh + (size_t)(blockIdx.y * 128 + 64 + crow) * K + kel;
  const unsigned short* pBl0 = Bl + (size_t)(blockIdx.y * 128 + crow) * K + kel;
  const unsigned short* pBl1 = Bl + (size_t)(blockIdx.y * 128 + 64 + crow) * K + kel;
  const int wb = (tid & 192) * 8;

  floatx4 acc[16];
  #pragma unroll
  for (int i = 0; i < 16; ++i) acc[i] = (floatx4){0.f, 0.f, 0.f, 0.f};

  const int mq = (w & 1) << 6;
  const int nq = (w >> 1) << 6;
  const int fr = lane & 15;
  const int fk = (lane >> 4) << 3;

  for (int kt = 0; kt < K; kt += 32) {
    __syncthreads();
    gll16(pAh0, sAh + wb); gll16(pAh1, sAh + 2048 + wb);
    gll16(pAl0, sAl + wb); gll16(pAl1, sAl + 2048 + wb);
    gll16(pBh0, sBh + wb); gll16(pBh1, sBh + 2048 + wb);
    gll16(pBl0, sBl + wb); gll16(pBl1, sBl + 2048 + wb);
    pAh0 += 32; pAh1 += 32; pAl0 += 32; pAl1 += 32;
    pBh0 += 32; pBh1 += 32; pBl0 += 32; pBl1 += 32;
    __syncthreads();

    bf16x8 ah[4], al[4], bh[4], bl[4];
    #pragma unroll
    for (int mi = 0; mi < 4; ++mi) {
      int off = (mq + mi * 16 + fr) * 32 + fk;
      ah[mi] = *(const bf16x8*)&sAh[off];
      al[mi] = *(const bf16x8*)&sAl[off];
    }
    #pragma unroll
    for (int ni = 0; ni < 4; ++ni) {
      int off = (nq + ni * 16 + fr) * 32 + fk;
      bh[ni] = *(const bf16x8*)&sBh[off];
      bl[ni] = *(const bf16x8*)&sBl[off];
    }
    #pragma unroll
    for (int mi = 0; mi < 4; ++mi)
      #pragma unroll
      for (int ni = 0; ni < 4; ++ni) {
        floatx4 c = acc[mi * 4 + ni];
        c = __builtin_amdgcn_mfma_f32_16x16x32_bf16(ah[mi], bh[ni], c, 0, 0, 0);
        c = __builtin_amdgcn_mfma_f32_16x16x32_bf16(ah[mi], bl[ni], c, 0, 0, 0);
        c = __builtin_amdgcn_mfma_f32_16x16x32_bf16(al[mi], bh[ni], c, 0, 0, 0);
        acc[mi * 4 + ni] = c;
      }
  }

  const int mbase = blockIdx.x * 128 + mq + ((lane >> 4) << 2);
  const int nbase = blockIdx.y * 128 + nq + (lane & 15);
  #pragma unroll
  for (int ni = 0; ni < 4; ++ni) {
    int n = nbase + ni * 16;
    if (n < nvalid) {
      float bs = bias[n];
      #pragma unroll
      for (int mi = 0; mi < 4; ++mi) {
        #pragma unroll
        for (int r = 0; r < 4; ++r) {
          int m = mbase + mi * 16 + r;
          float val = acc[mi * 4 + ni][r] + bs;
          if (act == 1)      val = val * (1.0f / (1.0f + __expf(-val)));
          else if (act == 2) val = 1.0f / (1.0f + __expf(-val));
          C[(size_t)m * ldc + n] = val;
        }
      }
    }
  }
}

// ---------------------------------------------------------------- depthwise conv(K=4,pad2) + silu + optional l2norm
__global__ __launch_bounds__(256)
void conv_kernel(const float* __restrict__ pre, const float* __restrict__ w,
                 float* __restrict__ out, int do_norm)
{
  __shared__ float red[4];
  const int bt  = blockIdx.x;
  const int t   = bt & (SEQ - 1);
  const int tid = threadIdx.x;
  const int c   = tid << 2;
  const float* rowp = pre + (size_t)bt * DIMC + c;
  const float4 z = make_float4(0.f, 0.f, 0.f, 0.f);
  float4 xm2 = (t >= 2)      ? *(const float4*)(rowp - 2 * DIMC) : z;
  float4 xm1 = (t >= 1)      ? *(const float4*)(rowp - DIMC)     : z;
  float4 x0  =                 *(const float4*)(rowp);
  float4 xp1 = (t + 1 < SEQ) ? *(const float4*)(rowp + DIMC)     : z;
  const float4 w0 = *(const float4*)(w + (size_t)(c + 0) * 4);
  const float4 w1 = *(const float4*)(w + (size_t)(c + 1) * 4);
  const float4 w2 = *(const float4*)(w + (size_t)(c + 2) * 4);
  const float4 w3 = *(const float4*)(w + (size_t)(c + 3) * 4);
  float y0 = xm2.x * w0.x + xm1.x * w0.y + x0.x * w0.z + xp1.x * w0.w;
  float y1 = xm2.y * w1.x + xm1.y * w1.y + x0.y * w1.z + xp1.y * w1.w;
  float y2 = xm2.z * w2.x + xm1.z * w2.y + x0.z * w2.z + xp1.z * w2.w;
  float y3 = xm2.w * w3.x + xm1.w * w3.y + x0.w * w3.z + xp1.w * w3.w;
  y0 = y0 * (1.0f / (1.0f + __expf(-y0)));
  y1 = y1 * (1.0f / (1.0f + __expf(-y1)));
  y2 = y2 * (1.0f / (1.0f + __expf(-y2)));
  y3 = y3 * (1.0f / (1.0f + __expf(-y3)));
  if (do_norm) {
    float ss = y0*y0 + y1*y1 + y2*y2 + y3*y3;
    #pragma unroll
    for (int off = 32; off >= 1; off >>= 1) ss += __shfl_xor(ss, off);
    if ((tid & 63) == 0) red[tid >> 6] = ss;
    __syncthreads();
    float tot = red[0] + red[1] + red[2] + red[3];
    float rn = 1.0f / (sqrtf(tot) + 1e-6f);
    y0 *= rn; y1 *= rn; y2 *= rn; y3 *= rn;
  }
  *(float4*)(out + (size_t)bt * DIMC + c) = make_float4(y0, y1, y2, y3);
}

// ---------------------------------------------------------------- gated delta scan, pass 1 (serial)
// 2-step fused recurrence (lookahead pair):
//   u1 = S0.k1, u2 = S0.k2, kap = k1.k2  (parallel dots)
//   c1 = b1 v1 - a1 b1 u1
//   c2 = b2 v2 - a2 b2 (a1 u2 + c1 kap)
//   S  = (a1 a2) S0 + (a2 c1) k1 + c2 k2
// One waitcnt/LDS-exposure per PAIR. Round-1-proven ordering:
// prefetch -> waitcnt -> read temps -> S-update -> swap.
#define PD 16
__global__ __launch_bounds__(64)
void scan2_kernel(const float* __restrict__ k, const float* __restrict__ v,
                  const float* __restrict__ ab, float* __restrict__ Cf,
                  float* __restrict__ SC)
{
  __shared__ float ring[PD][2][64];   // [slot][k|v][64]
  __shared__ float aS[SEQ];
  __shared__ float bSh[SEQ];
  const int blk = blockIdx.x;
  const int bh  = blk >> 3;           // b*16+h
  const int dg  = blk & 7;            // 8-row group
  const int b   = bh >> 4, h = bh & 15;
  const int tid = threadIdx.x;        // 0..63, one wave
  const int eh  = tid & 7;            // e-octant
  const int d   = dg * 8 + (tid >> 3);
  const int e0  = eh * 8;

  const float* abbase = ab + (size_t)b * SEQ * 32 + h;
  for (int i = tid; i < SEQ; i += 64) {
    aS[i]  = abbase[(size_t)i * 32];
    bSh[i] = abbase[(size_t)i * 32 + 16];
  }

  const size_t base = (size_t)b * SEQ * DIMC + h * 64;
  const float* kp = k + base + tid;
  const float* vp = v + base + tid;

  // zero checkpoint for chunk 0
  {
    float4 z4 = make_float4(0.f, 0.f, 0.f, 0.f);
    float4* dst0 = (float4*)&SC[(((size_t)bh * 32) * 64 + d) * 64 + e0];
    dst0[0] = z4; dst0[1] = z4;
  }

  #pragma unroll
  for (int pt = 0; pt < PD; ++pt) {
    gll4(kp + (size_t)pt * DIMC, &ring[pt][0][0]);
    gll4(vp + (size_t)pt * DIMC, &ring[pt][1][0]);
  }
  __builtin_amdgcn_s_waitcnt(WAIT_VM0);   // drain prologue
  asm volatile("" ::: "memory");

  float S[8];
  #pragma unroll
  for (int j = 0; j < 8; ++j) S[j] = 0.f;

  float* cfp = Cf + (size_t)bh * SEQ * 64 + d;

  // preload pair (0,1)
  float4 k1a = *(const float4*)&ring[0][0][e0];
  float4 k1b = *(const float4*)&ring[0][0][e0 + 4];
  float4 k2a = *(const float4*)&ring[1][0][e0];
  float4 k2b = *(const float4*)&ring[1][0][e0 + 4];
  float  v1  = ring[0][1][d];
  float  v2  = ring[1][1][d];
  float  a1  = aS[0], a2 = aS[1];
  float  b1  = bSh[0], b2 = bSh[1];

  for (int t = 0; t < SEQ; t += 2) {
    // ---- parallel dots from current regs
    float q0 = fmaf(S[0], k1a.x, S[4] * k1b.x);
    float q1 = fmaf(S[1], k1a.y, S[5] * k1b.y);
    float q2 = fmaf(S[2], k1a.z, S[6] * k1b.z);
    float q3 = fmaf(S[3], k1a.w, S[7] * k1b.w);
    float r0 = fmaf(S[0], k2a.x, S[4] * k2b.x);
    float r1 = fmaf(S[1], k2a.y, S[5] * k2b.y);
    float r2 = fmaf(S[2], k2a.z, S[6] * k2b.z);
    float r3 = fmaf(S[3], k2a.w, S[7] * k2b.w);
    float x0 = fmaf(k1a.x, k2a.x, k1b.x * k2b.x);
    float x1 = fmaf(k1a.y, k2a.y, k1b.y * k2b.y);
    float x2 = fmaf(k1a.z, k2a.z, k1b.z * k2b.z);
    float x3 = fmaf(k1a.w, k2a.w, k1b.w * k2b.w);
    float u1  = oct_sum((q0 + q1) + (q2 + q3));
    float u2  = oct_sum((r0 + r1) + (r2 + r3));
    float kap = oct_sum((x0 + x1) + (x2 + x3));

    // ---- scalar chain (2-step fusion)
    const float e1 = b1 * v1, f1 = a1 * b1;
    const float e2 = b2 * v2, f2 = a2 * b2;
    const float w2 = a1 * u2;
    const float G2 = a1 * a2;
    const float c1 = fmaf(-f1, u1, e1);
    const float c2 = fmaf(-f2, fmaf(c1, kap, w2), e2);
    const float d1 = a2 * c1;
    if (eh == 0) { cfp[(size_t)t * 64] = c1; cfp[(size_t)(t + 1) * 64] = c2; }
    asm volatile("" ::: "memory");          // stores stay before prefetch (FIFO count)

    // ---- prefetch pair (t+PD, t+PD+1)
    if (t < SEQ - PD) {
      const int s0 = t & (PD - 1);          // slot for t+PD
      const int s1 = (t + 1) & (PD - 1);
      gll4(kp + (size_t)(t + PD) * DIMC,     &ring[s0][0][0]);
      gll4(vp + (size_t)(t + PD) * DIMC,     &ring[s0][1][0]);
      gll4(kp + (size_t)(t + PD + 1) * DIMC, &ring[s1][0][0]);
      gll4(vp + (size_t)(t + PD + 1) * DIMC, &ring[s1][1][0]);
      asm volatile("" ::: "memory");
      __builtin_amdgcn_s_waitcnt(WAIT_VM42);  // pair (t+2) resident
    } else {
      asm volatile("" ::: "memory");
      __builtin_amdgcn_s_waitcnt(WAIT_VM0);
    }
    asm volatile("" ::: "memory");          // ds_reads below stay below waitcnt

    // ---- pipelined reads for pair (t+2) into temps
    const int sl2 = (t + 2) & (PD - 1);
    const int sl3 = (t + 3) & (PD - 1);
    const int tn  = (t + 2) & (SEQ - 1);
    const float4 k1a_n = *(const float4*)&ring[sl2][0][e0];
    const float4 k1b_n = *(const float4*)&ring[sl2][0][e0 + 4];
    const float4 k2a_n = *(const float4*)&ring[sl3][0][e0];
    const float4 k2b_n = *(const float4*)&ring[sl3][0][e0 + 4];
    const float  v1_n  = ring[sl2][1][d];
    const float  v2_n  = ring[sl3][1][d];
    const float2 a_n   = *(const float2*)&aS[tn];
    const float2 b_n   = *(const float2*)&bSh[tn];

    // ---- fused 2-step state update (overlaps the reads above)
    S[0] = fmaf(G2, S[0], fmaf(d1, k1a.x, c2 * k2a.x));
    S[1] = fmaf(G2, S[1], fmaf(d1, k1a.y, c2 * k2a.y));
    S[2] = fmaf(G2, S[2], fmaf(d1, k1a.z, c2 * k2a.z));
    S[3] = fmaf(G2, S[3], fmaf(d1, k1a.w, c2 * k2a.w));
    S[4] = fmaf(G2, S[4], fmaf(d1, k1b.x, c2 * k2b.x));
    S[5] = fmaf(G2, S[5], fmaf(d1, k1b.y, c2 * k2b.y));
    S[6] = fmaf(G2, S[6], fmaf(d1, k1b.z, c2 * k2b.z));
    S[7] = fmaf(G2, S[7], fmaf(d1, k1b.w, c2 * k2b.w));

    if (((t + 2) & 63) == 0 && (t + 2) < SEQ) {  // checkpoint entering chunk (t+2)>>6
      float4* dst = (float4*)&SC[(((size_t)bh * 32 + ((t + 2) >> 6)) * 64 + d) * 64 + e0];
      dst[0] = make_float4(S[0], S[1], S[2], S[3]);
      dst[1] = make_float4(S[4], S[5], S[6], S[7]);
    }

    k1a = k1a_n; k1b = k1b_n; k2a = k2a_n; k2b = k2b_n;
    v1 = v1_n; v2 = v2_n; a1 = a_n.x; a2 = a_n.y; b1 = b_n.x; b2 = b_n.y;
  }
}

// ---------------------------------------------------------------- gated delta scan, pass 2 (parallel)
__global__ __launch_bounds__(256)
void outp_kernel(const float* __restrict__ q, const float* __restrict__ k,
                 const float* __restrict__ Cf, const float* __restrict__ SC,
                 const float* __restrict__ ab, float* __restrict__ O)
{
  __shared__ float QsT[64 * 64];  // [d][t]
  __shared__ float CP [64 * 64];  // CsT [d][s], then reused as PT [s][t]
  __shared__ float Ks [64 * 64];  // [s][e]
  __shared__ float Zs [64 * 64];  // [d][e]
  __shared__ float av[64], Gv[64], rGv[64];

  const int c   = blockIdx.x;
  const int bh  = blockIdx.y;
  const int b   = bh >> 4, h = bh & 15;
  const int cs  = c << 6;
  const int tid = threadIdx.x;
  const int tl  = tid & 63, th = tid >> 6;

  {
    const float* qr = q  + ((size_t)(b * SEQ + cs + tl)) * DIMC + h * 64 + th * 16;
    const float* cr = Cf + ((size_t)bh * SEQ + cs + tl) * 64 + th * 16;
    #pragma unroll
    for (int u = 0; u < 4; ++u) {
      float4 qv = *(const float4*)(qr + u * 4);
      float4 cv = *(const float4*)(cr + u * 4);
      int dd = th * 16 + u * 4;
      QsT[(dd+0)*64 + tl] = qv.x; QsT[(dd+1)*64 + tl] = qv.y;
      QsT[(dd+2)*64 + tl] = qv.z; QsT[(dd+3)*64 + tl] = qv.w;
      CP [(dd+0)*64 + tl] = cv.x; CP [(dd+1)*64 + tl] = cv.y;
      CP [(dd+2)*64 + tl] = cv.z; CP [(dd+3)*64 + tl] = cv.w;
    }
    const float* kr = k  + ((size_t)(b * SEQ + cs + tl)) * DIMC + h * 64 + th * 16;
    const float* zr = SC + (((size_t)bh * 32 + c) * 64 + tl) * 64 + th * 16;
    #pragma unroll
    for (int u = 0; u < 4; ++u) {
      *(float4*)&Ks[tl * 64 + th * 16 + u * 4] = *(const float4*)(kr + u * 4);
      *(float4*)&Zs[tl * 64 + th * 16 + u * 4] = *(const float4*)(zr + u * 4);
    }
    if (tid < 64) av[tid] = ab[((size_t)(b * SEQ + cs + tid)) * 32 + h];
  }
  __syncthreads();
  if (tid == 0) {
    float g = 1.f;
    for (int t = 0; t < 64; ++t) { g *= av[t]; Gv[t] = fmaxf(g, 1e-37f); }
  }
  __syncthreads();
  if (tid < 64) rGv[tid] = 1.0f / Gv[tid];
  __syncthreads();

  const int tq = (tid >> 4) << 2;         // 0,4,...,60
  const int s0 = (tid & 15) << 2;

  float p[4][4] = {{0.f}};
  #pragma unroll 4
  for (int dd = 0; dd < 64; ++dd) {
    const float4 qv = *(const float4*)&QsT[dd * 64 + tq];
    const float4 cv = *(const float4*)&CP [dd * 64 + s0];
    const float qa[4] = {qv.x, qv.y, qv.z, qv.w};
    const float ca[4] = {cv.x, cv.y, cv.z, cv.w};
    #pragma unroll
    for (int i = 0; i < 4; ++i)
      #pragma unroll
      for (int j = 0; j < 4; ++j)
        p[i][j] = fmaf(qa[i], ca[j], p[i][j]);
  }
  __syncthreads();

  #pragma unroll
  for (int i = 0; i < 4; ++i) {
    const float gt = Gv[tq + i];
    #pragma unroll
    for (int j = 0; j < 4; ++j) {
      float vsc = (s0 + j <= tq + i) ? p[i][j] * gt * rGv[s0 + j] : 0.f;
      CP[(s0 + j) * 64 + (tq + i)] = vsc;
    }
  }
  __syncthreads();

  const int e0 = s0;
  float o[4][4] = {{0.f}};
  #pragma unroll 4
  for (int ss = 0; ss < 64; ++ss) {
    const float4 pv = *(const float4*)&CP[ss * 64 + tq];
    const float4 kv = *(const float4*)&Ks[ss * 64 + e0];
    const float pa[4] = {pv.x, pv.y, pv.z, pv.w};
    const float ka[4] = {kv.x, kv.y, kv.z, kv.w};
    #pragma unroll
    for (int i = 0; i < 4; ++i)
      #pragma unroll
      for (int j = 0; j < 4; ++j)
        o[i][j] = fmaf(pa[i], ka[j], o[i][j]);
  }
  float zt[4][4] = {{0.f}};
  #pragma unroll 4
  for (int dd = 0; dd < 64; ++dd) {
    const float4 qv = *(const float4*)&QsT[dd * 64 + tq];
    const float4 zv = *(const float4*)&Zs[dd * 64 + e0];
    const float qa[4] = {qv.x, qv.y, qv.z, qv.w};
    const float za[4] = {zv.x, zv.y, zv.z, zv.w};
    #pragma unroll
    for (int i = 0; i < 4; ++i)
      #pragma unroll
      for (int j = 0; j < 4; ++j)
        zt[i][j] = fmaf(qa[i], za[j], zt[i][j]);
  }
  #pragma unroll
  for (int i = 0; i < 4; ++i) {
    const float gt = Gv[tq + i];
    float4 res;
    res.x = fmaf(gt, zt[i][0], o[i][0]);
    res.y = fmaf(gt, zt[i][1], o[i][1]);
    res.z = fmaf(gt, zt[i][2], o[i][2]);
    res.w = fmaf(gt, zt[i][3], o[i][3]);
    *(float4*)(O + ((size_t)(b * SEQ + cs + tq + i)) * DIMC + h * 64 + e0) = res;
  }
}

// ---------------------------------------------------------------- host
extern "C" void kernel_launch(void* const* d_in, const int* in_sizes, int n_in,
                              void* d_out, int out_size, void* d_ws, size_t ws_size,
                              hipStream_t stream)
{
  const float* x  = (const float*)d_in[0];
  const float* Wq = (const float*)d_in[1];
  const float* bq = (const float*)d_in[2];
  const float* Wk = (const float*)d_in[3];
  const float* bk = (const float*)d_in[4];
  const float* Wv = (const float*)d_in[5];
  const float* bv = (const float*)d_in[6];
  const float* Wa = (const float*)d_in[7];
  const float* ba = (const float*)d_in[8];
  const float* Wb = (const float*)d_in[9];
  const float* bb = (const float*)d_in[10];
  const float* cq = (const float*)d_in[11];
  const float* ck = (const float*)d_in[12];
  const float* cv = (const float*)d_in[13];
  const float* Wo = (const float*)d_in[14];
  const float* bo = (const float*)d_in[15];
  float* out = (float*)d_out;
  float* ws  = (float*)d_ws;

  const size_t per_b = (size_t)SEQ * DIMC;     // 2,097,152
  const size_t wsz   = (size_t)DIMC * DIMC;    // 1,048,576

  int bc = BATCH;
  while (bc > 1) {
    size_t fl = 4 * (size_t)bc * per_b + (size_t)bc * SEQ * 32 + 128 * 1024 + 128;
    size_t us = 2 * (size_t)bc * per_b + 8 * wsz + 2 * 128 * 1024;
    if (fl * 4 + us * 2 <= ws_size) break;
    bc >>= 1;
  }

  float* P   = ws;
  float* qb  = P  + (size_t)bc * per_b;
  float* kb  = qb + (size_t)bc * per_b;
  float* vb  = kb + (size_t)bc * per_b;
  float* abb = vb + (size_t)bc * per_b;
  float* Wab = abb + (size_t)bc * SEQ * 32;
  float* bab = Wab + 128 * 1024;
  unsigned short* xh   = (unsigned short*)(bab + 128);
  unsigned short* xl   = xh  + (size_t)bc * per_b;
  unsigned short* wqh  = xl  + (size_t)bc * per_b;
  unsigned short* wql  = wqh + wsz;
  unsigned short* wkh  = wql + wsz;
  unsigned short* wkl  = wkh + wsz;
  unsigned short* wvh  = wkl + wsz;
  unsigned short* wvl  = wvh + wsz;
  unsigned short* woh  = wvl + wsz;
  unsigned short* wol  = woh + wsz;
  unsigned short* wabh = wol + wsz;
  unsigned short* wabl = wabh + 128 * 1024;

  float* Cf  = (float*)xh;
  float* SCp = P;

  pack_ab_kernel<<<513, 256, 0, stream>>>(Wa, ba, Wb, bb, Wab, bab);
  cvt_split<<<(int)(wsz / 4 + 255) / 256, 256, 0, stream>>>(Wq, wqh, wql, (int)(wsz / 4));
  cvt_split<<<(int)(wsz / 4 + 255) / 256, 256, 0, stream>>>(Wk, wkh, wkl, (int)(wsz / 4));
  cvt_split<<<(int)(wsz / 4 + 255) / 256, 256, 0, stream>>>(Wv, wvh, wvl, (int)(wsz / 4));
  cvt_split<<<(int)(wsz / 4 + 255) / 256, 256, 0, stream>>>(Wo, woh, wol, (int)(wsz / 4));
  cvt_split<<<(128 * 1024 / 4 + 255) / 256, 256, 0, stream>>>(Wab, wabh, wabl, 128 * 1024 / 4);

  for (int b0 = 0; b0 < BATCH; b0 += bc) {
    const float* xb = x + (size_t)b0 * per_b;
    const int M = bc * SEQ;
    const int n4 = (int)((size_t)bc * per_b / 4);
    dim3 gg(M / 128, DIMC / 128);
    dim3 gab(M / 128, 1);

    cvt_split<<<(n4 + 255) / 256, 256, 0, stream>>>(xb, xh, xl, n4);

    gemm_bf16x3<<<gg, 256, 0, stream>>>(xh, xl, wqh, wql, bq, P, DIMC, DIMC, DIMC, 1);
    conv_kernel<<<dim3(M), 256, 0, stream>>>(P, cq, qb, 1);
    gemm_bf16x3<<<gg, 256, 0, stream>>>(xh, xl, wkh, wkl, bk, P, DIMC, DIMC, DIMC, 1);
    conv_kernel<<<dim3(M), 256, 0, stream>>>(P, ck, kb, 1);
    gemm_bf16x3<<<gg, 256, 0, stream>>>(xh, xl, wvh, wvl, bv, P, DIMC, DIMC, DIMC, 1);
    conv_kernel<<<dim3(M), 256, 0, stream>>>(P, cv, vb, 0);
    gemm_bf16x3<<<gab, 256, 0, stream>>>(xh, xl, wabh, wabl, bab, abb, DIMC, 32, 32, 2);
    scan2_kernel<<<dim3(bc * NHEAD * 8), 64, 0, stream>>>(kb, vb, abb, Cf, SCp);
    outp_kernel<<<dim3(SEQ / 64, bc * NHEAD), 256, 0, stream>>>(qb, kb, Cf, SCp, abb, vb);
    cvt_split<<<(n4 + 255) / 256, 256, 0, stream>>>(vb, xh, xl, n4);
    gemm_bf16x3<<<gg, 256, 0, stream>>>(xh, xl, woh, wol, bo, out + (size_t)b0 * per_b, DIMC, DIMC, DIMC, 0);
  }
}

// Round 5
// 1561.682 us; speedup vs baseline: 1.3891x; 1.0373x over previous
//
#include <hip/hip_runtime.h>

#define DIMC 1024
#define SEQ  2048
#define NHEAD 16
#define BATCH 8

// ---------------------------------------------------------------- helpers
__device__ __forceinline__ void gll16u(const unsigned short* g, unsigned short* l) {
  __builtin_amdgcn_global_load_lds(
      (const __attribute__((address_space(1))) void*)g,
      (__attribute__((address_space(3))) void*)l, 16, 0, 0);
}
__device__ __forceinline__ void gll16f(const float* g, float* l) {
  __builtin_amdgcn_global_load_lds(
      (const __attribute__((address_space(1))) void*)g,
      (__attribute__((address_space(3))) void*)l, 16, 0, 0);
}

// waitcnt immediates (gfx9 encoding: vm[3:0]=b3:0, exp=b6:4, lgkm=b11:8, vm[5:4]=b15:14)
// ring = 8 pair-slots, 1 kv load per pair. Needed load (pair t+2, read this iter)
// has exactly 7 younger loads (+<=4 boundary stores) -> wait vmcnt<=7.
#define WAIT_VM7    0x0F77  // vmcnt<=7
#define WAIT_VM0    0x0F70  // vmcnt<=0

// fp32 <-> bf16 (RNE)
__device__ __forceinline__ unsigned short f2bf(float f) {
  unsigned u = __float_as_uint(f);
  return (unsigned short)((u + 0x7fffu + ((u >> 16) & 1u)) >> 16);
}
__device__ __forceinline__ float bf2f(unsigned short h) {
  return __uint_as_float(((unsigned)h) << 16);
}

typedef __attribute__((ext_vector_type(8))) short  bf16x8;
typedef __attribute__((ext_vector_type(4))) float  floatx4;

// sum over 8 contiguous (8-aligned) lanes, pure DPP: ^1, ^2, then half-row mirror
__device__ __forceinline__ float oct_sum(float x) {
  int t1 = __builtin_amdgcn_update_dpp(0, __float_as_int(x), 0xB1, 0xF, 0xF, true);   // quad_perm(1,0,3,2)
  float x1 = x + __int_as_float(t1);
  int t2 = __builtin_amdgcn_update_dpp(0, __float_as_int(x1), 0x4E, 0xF, 0xF, true);  // quad_perm(2,3,0,1)
  float x2 = x1 + __int_as_float(t2);
  int t3 = __builtin_amdgcn_update_dpp(0, __float_as_int(x2), 0x141, 0xF, 0xF, true); // row_half_mirror
  return x2 + __int_as_float(t3);
}

// ---------------------------------------------------------------- split fp32 -> bf16 hi/lo
__global__ __launch_bounds__(256)
void cvt_split(const float* __restrict__ in, unsigned short* __restrict__ hi,
               unsigned short* __restrict__ lo, int n4)
{
  int i = blockIdx.x * 256 + threadIdx.x;
  if (i >= n4) return;
  float4 f = ((const float4*)in)[i];
  unsigned short h0 = f2bf(f.x), h1 = f2bf(f.y), h2 = f2bf(f.z), h3 = f2bf(f.w);
  unsigned short l0 = f2bf(f.x - bf2f(h0)), l1 = f2bf(f.y - bf2f(h1));
  unsigned short l2 = f2bf(f.z - bf2f(h2)), l3 = f2bf(f.w - bf2f(h3));
  ushort4 H; H.x = h0; H.y = h1; H.z = h2; H.w = h3;
  ushort4 L; L.x = l0; L.y = l1; L.z = l2; L.w = l3;
  ((ushort4*)hi)[i] = H;
  ((ushort4*)lo)[i] = L;
}

// ---------------------------------------------------------------- pack Wa/Wb into padded 128x1024
__global__ void pack_ab_kernel(const float* __restrict__ Wa, const float* __restrict__ ba,
                               const float* __restrict__ Wb, const float* __restrict__ bb,
                               float* __restrict__ Wab, float* __restrict__ bab)
{
  int i = blockIdx.x * 256 + threadIdx.x;
  if (i < 128 * 1024) {
    int row = i >> 10, col = i & 1023;
    float v = 0.0f;
    if (row < 16) v = Wa[(row << 10) + col];
    else if (row < 32) v = Wb[((row - 16) << 10) + col];
    Wab[i] = v;
  } else {
    int j = i - 128 * 1024;
    if (j < 128) {
      float v = 0.0f;
      if (j < 16) v = ba[j];
      else if (j < 32) v = bb[j - 16];
      bab[j] = v;
    }
  }
}

// ---------------------------------------------------------------- split-bf16 MFMA GEMM
__global__ __launch_bounds__(256, 2)
void gemm_bf16x3(const unsigned short* __restrict__ Ah, const unsigned short* __restrict__ Al,
                 const unsigned short* __restrict__ Bh, const unsigned short* __restrict__ Bl,
                 const float* __restrict__ bias, float* __restrict__ C,
                 int K, int ldc, int nvalid, int act)
{
  __shared__ unsigned short sAh[4096], sAl[4096], sBh[4096], sBl[4096];
  const int tid  = threadIdx.x;
  const int lane = tid & 63;
  const int w    = tid >> 6;

  const int crow = tid >> 2;
  const int kel  = (tid & 3) << 3;
  const unsigned short* pAh0 = Ah + (size_t)(blockIdx.x * 128 + crow) * K + kel;
  const unsigned short* pAh1 = Ah + (size_t)(blockIdx.x * 128 + 64 + crow) * K + kel;
  const unsigned short* pAl0 = Al + (size_t)(blockIdx.x * 128 + crow) * K + kel;
  const unsigned short* pAl1 = Al + (size_t)(blockIdx.x * 128 + 64 + crow) * K + kel;
  const unsigned short* pBh0 = Bh + (size_t)(blockIdx.y * 128 + crow) * K + kel;
  const unsigned short* pBh1 = Bh + (size_t)(blockIdx.y * 128 + 64 + crow) * K + kel;
  const unsigned short* pBl0 = Bl + (size_t)(blockIdx.y * 128 + crow) * K + kel;
  const unsigned short* pBl1 = Bl + (size_t)(blockIdx.y * 128 + 64 + crow) * K + kel;
  const int wb = (tid & 192) * 8;

  floatx4 acc[16];
  #pragma unroll
  for (int i = 0; i < 16; ++i) acc[i] = (floatx4){0.f, 0.f, 0.f, 0.f};

  const int mq = (w & 1) << 6;
  const int nq = (w >> 1) << 6;
  const int fr = lane & 15;
  const int fk = (lane >> 4) << 3;

  for (int kt = 0; kt < K; kt += 32) {
    __syncthreads();
    gll16u(pAh0, sAh + wb); gll16u(pAh1, sAh + 2048 + wb);
    gll16u(pAl0, sAl + wb); gll16u(pAl1, sAl + 2048 + wb);
    gll16u(pBh0, sBh + wb); gll16u(pBh1, sBh + 2048 + wb);
    gll16u(pBl0, sBl + wb); gll16u(pBl1, sBl + 2048 + wb);
    pAh0 += 32; pAh1 += 32; pAl0 += 32; pAl1 += 32;
    pBh0 += 32; pBh1 += 32; pBl0 += 32; pBl1 += 32;
    __syncthreads();

    bf16x8 ah[4], al[4], bh[4], bl[4];
    #pragma unroll
    for (int mi = 0; mi < 4; ++mi) {
      int off = (mq + mi * 16 + fr) * 32 + fk;
      ah[mi] = *(const bf16x8*)&sAh[off];
      al[mi] = *(const bf16x8*)&sAl[off];
    }
    #pragma unroll
    for (int ni = 0; ni < 4; ++ni) {
      int off = (nq + ni * 16 + fr) * 32 + fk;
      bh[ni] = *(const bf16x8*)&sBh[off];
      bl[ni] = *(const bf16x8*)&sBl[off];
    }
    #pragma unroll
    for (int mi = 0; mi < 4; ++mi)
      #pragma unroll
      for (int ni = 0; ni < 4; ++ni) {
        floatx4 c = acc[mi * 4 + ni];
        c = __builtin_amdgcn_mfma_f32_16x16x32_bf16(ah[mi], bh[ni], c, 0, 0, 0);
        c = __builtin_amdgcn_mfma_f32_16x16x32_bf16(ah[mi], bl[ni], c, 0, 0, 0);
        c = __builtin_amdgcn_mfma_f32_16x16x32_bf16(al[mi], bh[ni], c, 0, 0, 0);
        acc[mi * 4 + ni] = c;
      }
  }

  const int mbase = blockIdx.x * 128 + mq + ((lane >> 4) << 2);
  const int nbase = blockIdx.y * 128 + nq + (lane & 15);
  #pragma unroll
  for (int ni = 0; ni < 4; ++ni) {
    int n = nbase + ni * 16;
    if (n < nvalid) {
      float bs = bias[n];
      #pragma unroll
      for (int mi = 0; mi < 4; ++mi) {
        #pragma unroll
        for (int r = 0; r < 4; ++r) {
          int m = mbase + mi * 16 + r;
          float val = acc[mi * 4 + ni][r] + bs;
          if (act == 1)      val = val * (1.0f / (1.0f + __expf(-val)));
          else if (act == 2) val = 1.0f / (1.0f + __expf(-val));
          C[(size_t)m * ldc + n] = val;
        }
      }
    }
  }
}

// ---------------------------------------------------------------- depthwise conv(K=4,pad2) + silu + optional l2norm
// mode 0: plain [b][t][1024] write.  mode 1: packed k -> kv[bh][t][0:64).
// mode 2: packed v -> kv[bh][t][64:128).
__global__ __launch_bounds__(256)
void conv_kernel(const float* __restrict__ pre, const float* __restrict__ w,
                 float* __restrict__ out, int do_norm, int mode)
{
  __shared__ float red[4];
  const int bt  = blockIdx.x;
  const int t   = bt & (SEQ - 1);
  const int tid = threadIdx.x;
  const int c   = tid << 2;
  const float* rowp = pre + (size_t)bt * DIMC + c;
  const float4 z = make_float4(0.f, 0.f, 0.f, 0.f);
  float4 xm2 = (t >= 2)      ? *(const float4*)(rowp - 2 * DIMC) : z;
  float4 xm1 = (t >= 1)      ? *(const float4*)(rowp - DIMC)     : z;
  float4 x0  =                 *(const float4*)(rowp);
  float4 xp1 = (t + 1 < SEQ) ? *(const float4*)(rowp + DIMC)     : z;
  const float4 w0 = *(const float4*)(w + (size_t)(c + 0) * 4);
  const float4 w1 = *(const float4*)(w + (size_t)(c + 1) * 4);
  const float4 w2 = *(const float4*)(w + (size_t)(c + 2) * 4);
  const float4 w3 = *(const float4*)(w + (size_t)(c + 3) * 4);
  float y0 = xm2.x * w0.x + xm1.x * w0.y + x0.x * w0.z + xp1.x * w0.w;
  float y1 = xm2.y * w1.x + xm1.y * w1.y + x0.y * w1.z + xp1.y * w1.w;
  float y2 = xm2.z * w2.x + xm1.z * w2.y + x0.z * w2.z + xp1.z * w2.w;
  float y3 = xm2.w * w3.x + xm1.w * w3.y + x0.w * w3.z + xp1.w * w3.w;
  y0 = y0 * (1.0f / (1.0f + __expf(-y0)));
  y1 = y1 * (1.0f / (1.0f + __expf(-y1)));
  y2 = y2 * (1.0f / (1.0f + __expf(-y2)));
  y3 = y3 * (1.0f / (1.0f + __expf(-y3)));
  if (do_norm) {
    float ss = y0*y0 + y1*y1 + y2*y2 + y3*y3;
    #pragma unroll
    for (int off = 32; off >= 1; off >>= 1) ss += __shfl_xor(ss, off);
    if ((tid & 63) == 0) red[tid >> 6] = ss;
    __syncthreads();
    float tot = red[0] + red[1] + red[2] + red[3];
    float rn = 1.0f / (sqrtf(tot) + 1e-6f);
    y0 *= rn; y1 *= rn; y2 *= rn; y3 *= rn;
  }
  float4 res = make_float4(y0, y1, y2, y3);
  if (mode == 0) {
    *(float4*)(out + (size_t)bt * DIMC + c) = res;
  } else {
    const int b = bt >> 11;           // SEQ = 2048
    const int h = c >> 6, e = c & 63;
    const int koff = (mode == 1) ? 0 : 64;
    *(float4*)(out + (((size_t)(b * 16 + h)) * SEQ + t) * 128 + koff + e) = res;
  }
}

// ---------------------------------------------------------------- gated delta scan, pass 1 (serial)
// 2-step fused recurrence (R3-proven math). New memory plan:
//  - kv packed [bh][t][128]: ONE gll16 (1024B) fetches a whole pair (k,v) x 2 steps.
//  - coef buffered in LDS, flushed once per 64-step chunk to Cf[bh][chunk][64d][64t].
//  - vmem ops/pair: 6 -> ~1.1 (the R1/R3 ~60cy-per-vmem-op stall driver).
// Grid: dim3(nbh, 8): all 8 d-slice blocks of a bh land on one XCD (ids differ by nbh%8==0).
#define PD 16
__global__ __launch_bounds__(64)
void scan2_kernel(const float* __restrict__ kv, const float* __restrict__ ab,
                  float* __restrict__ Cf, float* __restrict__ SC)
{
  __shared__ float ring[8][256];      // [pair-slot][ k_t | v_t | k_t+1 | v_t+1 ]
  __shared__ float aS[SEQ];
  __shared__ float bSh[SEQ];
  __shared__ float cbuf[8][72];       // per-chunk coef [8 local d][64 t] (+pad)
  const int bh  = blockIdx.x;         // b*16+h
  const int dg  = blockIdx.y;         // 8-row group
  const int b   = bh >> 4, h = bh & 15;
  const int tid = threadIdx.x;        // 0..63, one wave
  const int eh  = tid & 7;            // e-octant
  const int dl  = tid >> 3;           // local d 0..7
  const int d   = dg * 8 + dl;        // global state row 0..63
  const int e0  = eh * 8;

  const float* abbase = ab + (size_t)b * SEQ * 32 + h;
  for (int i = tid; i < SEQ; i += 64) {
    aS[i]  = abbase[(size_t)i * 32];
    bSh[i] = abbase[(size_t)i * 32 + 16];
  }

  const float* kvsrc = kv + (size_t)bh * SEQ * 128 + tid * 4;  // per-lane 16B slice

  // zero checkpoint for chunk 0
  {
    float4 z4 = make_float4(0.f, 0.f, 0.f, 0.f);
    float4* dst0 = (float4*)&SC[(((size_t)bh * 32) * 64 + d) * 64 + e0];
    dst0[0] = z4; dst0[1] = z4;
  }

  #pragma unroll
  for (int pp = 0; pp < 8; ++pp)
    gll16f(kvsrc + (size_t)pp * 256, &ring[pp][0]);
  __builtin_amdgcn_s_waitcnt(WAIT_VM0);   // drain prologue (incl. zero-ckpt store)
  asm volatile("" ::: "memory");

  float S[8];
  #pragma unroll
  for (int j = 0; j < 8; ++j) S[j] = 0.f;

  // preload pair (0,1) from slot 0
  float4 k1a = *(const float4*)&ring[0][e0];
  float4 k1b = *(const float4*)&ring[0][e0 + 4];
  float  v1  = ring[0][64 + d];
  float4 k2a = *(const float4*)&ring[0][128 + e0];
  float4 k2b = *(const float4*)&ring[0][128 + e0 + 4];
  float  v2  = ring[0][192 + d];
  float  a1  = aS[0], a2 = aS[1];
  float  b1  = bSh[0], b2 = bSh[1];

  for (int t = 0; t < SEQ; t += 2) {
    // ---- parallel dots from current regs
    float q0 = fmaf(S[0], k1a.x, S[4] * k1b.x);
    float q1 = fmaf(S[1], k1a.y, S[5] * k1b.y);
    float q2 = fmaf(S[2], k1a.z, S[6] * k1b.z);
    float q3 = fmaf(S[3], k1a.w, S[7] * k1b.w);
    float r0 = fmaf(S[0], k2a.x, S[4] * k2b.x);
    float r1 = fmaf(S[1], k2a.y, S[5] * k2b.y);
    float r2 = fmaf(S[2], k2a.z, S[6] * k2b.z);
    float r3 = fmaf(S[3], k2a.w, S[7] * k2b.w);
    float x0 = fmaf(k1a.x, k2a.x, k1b.x * k2b.x);
    float x1 = fmaf(k1a.y, k2a.y, k1b.y * k2b.y);
    float x2 = fmaf(k1a.z, k2a.z, k1b.z * k2b.z);
    float x3 = fmaf(k1a.w, k2a.w, k1b.w * k2b.w);
    float u1  = oct_sum((q0 + q1) + (q2 + q3));
    float u2  = oct_sum((r0 + r1) + (r2 + r3));
    float kap = oct_sum((x0 + x1) + (x2 + x3));

    // ---- scalar chain (2-step fusion)
    const float e1c = b1 * v1, f1 = a1 * b1;
    const float e2c = b2 * v2, f2 = a2 * b2;
    const float w2c = a1 * u2;
    const float G2  = a1 * a2;
    const float c1  = fmaf(-f1, u1, e1c);
    const float c2  = fmaf(-f2, fmaf(c1, kap, w2c), e2c);
    const float d1  = a2 * c1;
    if (eh == 0) {                      // LDS-buffered coef (one b64 write)
      float2* cw = (float2*)&cbuf[dl][t & 63];
      *cw = make_float2(c1, c2);
    }

    // ---- prefetch pair (t+PD, t+PD+1): ONE gll16
    asm volatile("" ::: "memory");
    if (t < SEQ - PD) {
      const int slot = (t >> 1) & 7;    // slot of pair t (last read at iter t-2)
      gll16f(kvsrc + (size_t)(t + PD) * 128, &ring[slot][0]);
      asm volatile("" ::: "memory");
      __builtin_amdgcn_s_waitcnt(WAIT_VM7);   // pair (t+2) resident
    } else {
      asm volatile("" ::: "memory");
      __builtin_amdgcn_s_waitcnt(WAIT_VM0);
    }
    asm volatile("" ::: "memory");      // ds_reads below stay below waitcnt

    // ---- pipelined reads for pair (t+2) into temps
    const int sl = ((t >> 1) + 1) & 7;
    const int tn = (t + 2) & (SEQ - 1);
    const float4 k1a_n = *(const float4*)&ring[sl][e0];
    const float4 k1b_n = *(const float4*)&ring[sl][e0 + 4];
    const float  v1_n  = ring[sl][64 + d];
    const float4 k2a_n = *(const float4*)&ring[sl][128 + e0];
    const float4 k2b_n = *(const float4*)&ring[sl][128 + e0 + 4];
    const float  v2_n  = ring[sl][192 + d];
    const float2 a_n   = *(const float2*)&aS[tn];
    const float2 b_n   = *(const float2*)&bSh[tn];

    // ---- fused 2-step state update (overlaps the reads above)
    S[0] = fmaf(G2, S[0], fmaf(d1, k1a.x, c2 * k2a.x));
    S[1] = fmaf(G2, S[1], fmaf(d1, k1a.y, c2 * k2a.y));
    S[2] = fmaf(G2, S[2], fmaf(d1, k1a.z, c2 * k2a.z));
    S[3] = fmaf(G2, S[3], fmaf(d1, k1a.w, c2 * k2a.w));
    S[4] = fmaf(G2, S[4], fmaf(d1, k1b.x, c2 * k2b.x));
    S[5] = fmaf(G2, S[5], fmaf(d1, k1b.y, c2 * k2b.y));
    S[6] = fmaf(G2, S[6], fmaf(d1, k1b.z, c2 * k2b.z));
    S[7] = fmaf(G2, S[7], fmaf(d1, k1b.w, c2 * k2b.w));

    if (((t + 2) & 63) == 0) {
      // flush chunk c = t>>6 : lane l stores d2 = dg*8+(l>>3), t-span (l&7)*8..+8
      const int cix  = t >> 6;
      const int d2l  = tid >> 3;
      const int toff = (tid & 7) << 3;
      float* dst = Cf + (((size_t)bh * 32 + cix) * 64 + dg * 8 + d2l) * 64 + toff;
      float4 f0 = *(const float4*)&cbuf[d2l][toff];
      float4 f1 = *(const float4*)&cbuf[d2l][toff + 4];
      *(float4*)dst       = f0;
      *(float4*)(dst + 4) = f1;
      if ((t + 2) < SEQ) {              // checkpoint entering chunk (t+2)>>6
        float4* ck = (float4*)&SC[(((size_t)bh * 32 + ((t + 2) >> 6)) * 64 + d) * 64 + e0];
        ck[0] = make_float4(S[0], S[1], S[2], S[3]);
        ck[1] = make_float4(S[4], S[5], S[6], S[7]);
      }
    }

    k1a = k1a_n; k1b = k1b_n; k2a = k2a_n; k2b = k2b_n;
    v1 = v1_n; v2 = v2_n; a1 = a_n.x; a2 = a_n.y; b1 = b_n.x; b2 = b_n.y;
  }
}

// ---------------------------------------------------------------- gated delta scan, pass 2 (parallel)
// Cf layout is now [bh][chunk][64d][64t] -> CP tile is a direct coalesced copy.
// K tile read from packed kv[bh][t][0:64).
__global__ __launch_bounds__(256)
void outp_kernel(const float* __restrict__ q, const float* __restrict__ kv,
                 const float* __restrict__ Cf, const float* __restrict__ SC,
                 const float* __restrict__ ab, float* __restrict__ O)
{
  __shared__ float QsT[64 * 64];  // [d][t]
  __shared__ float CP [64 * 64];  // CsT [d][s], then reused as PT [s][t]
  __shared__ float Ks [64 * 64];  // [s][e]
  __shared__ float Zs [64 * 64];  // [d][e]
  __shared__ float av[64], Gv[64], rGv[64];

  const int c   = blockIdx.x;
  const int bh  = blockIdx.y;
  const int b   = bh >> 4, h = bh & 15;
  const int cs  = c << 6;
  const int tid = threadIdx.x;
  const int tl  = tid & 63, th = tid >> 6;

  {
    const float* qr = q + ((size_t)(b * SEQ + cs + tl)) * DIMC + h * 64 + th * 16;
    #pragma unroll
    for (int u = 0; u < 4; ++u) {
      float4 qv = *(const float4*)(qr + u * 4);
      int dd = th * 16 + u * 4;
      QsT[(dd+0)*64 + tl] = qv.x; QsT[(dd+1)*64 + tl] = qv.y;
      QsT[(dd+2)*64 + tl] = qv.z; QsT[(dd+3)*64 + tl] = qv.w;
    }
    const float* cr = Cf + ((size_t)bh * 32 + c) * 4096;      // [64d][64t], direct
    #pragma unroll
    for (int u = 0; u < 4; ++u)
      *(float4*)&CP[tid * 16 + u * 4] = *(const float4*)(cr + tid * 16 + u * 4);
    const float* kr = kv + ((size_t)bh * SEQ + cs + tl) * 128 + th * 16;
    const float* zr = SC + (((size_t)bh * 32 + c) * 64 + tl) * 64 + th * 16;
    #pragma unroll
    for (int u = 0; u < 4; ++u) {
      *(float4*)&Ks[tl * 64 + th * 16 + u * 4] = *(const float4*)(kr + u * 4);
      *(float4*)&Zs[tl * 64 + th * 16 + u * 4] = *(const float4*)(zr + u * 4);
    }
    if (tid < 64) av[tid] = ab[((size_t)(b * SEQ + cs + tid)) * 32 + h];
  }
  __syncthreads();
  if (tid == 0) {
    float g = 1.f;
    for (int t = 0; t < 64; ++t) { g *= av[t]; Gv[t] = fmaxf(g, 1e-37f); }
  }
  __syncthreads();
  if (tid < 64) rGv[tid] = 1.0f / Gv[tid];
  __syncthreads();

  const int tq = (tid >> 4) << 2;         // 0,4,...,60
  const int s0 = (tid & 15) << 2;

  float p[4][4] = {{0.f}};
  #pragma unroll 4
  for (int dd = 0; dd < 64; ++dd) {
    const float4 qv = *(const float4*)&QsT[dd * 64 + tq];
    const float4 cv = *(const float4*)&CP [dd * 64 + s0];
    const float qa[4] = {qv.x, qv.y, qv.z, qv.w};
    const float ca[4] = {cv.x, cv.y, cv.z, cv.w};
    #pragma unroll
    for (int i = 0; i < 4; ++i)
      #pragma unroll
      for (int j = 0; j < 4; ++j)
        p[i][j] = fmaf(qa[i], ca[j], p[i][j]);
  }
  __syncthreads();

  #pragma unroll
  for (int i = 0; i < 4; ++i) {
    const float gt = Gv[tq + i];
    #pragma unroll
    for (int j = 0; j < 4; ++j) {
      float vsc = (s0 + j <= tq + i) ? p[i][j] * gt * rGv[s0 + j] : 0.f;
      CP[(s0 + j) * 64 + (tq + i)] = vsc;
    }
  }
  __syncthreads();

  const int e0 = s0;
  float o[4][4] = {{0.f}};
  #pragma unroll 4
  for (int ss = 0; ss < 64; ++ss) {
    const float4 pv = *(const float4*)&CP[ss * 64 + tq];
    const float4 kvv = *(const float4*)&Ks[ss * 64 + e0];
    const float pa[4] = {pv.x, pv.y, pv.z, pv.w};
    const float ka[4] = {kvv.x, kvv.y, kvv.z, kvv.w};
    #pragma unroll
    for (int i = 0; i < 4; ++i)
      #pragma unroll
      for (int j = 0; j < 4; ++j)
        o[i][j] = fmaf(pa[i], ka[j], o[i][j]);
  }
  float zt[4][4] = {{0.f}};
  #pragma unroll 4
  for (int dd = 0; dd < 64; ++dd) {
    const float4 qv = *(const float4*)&QsT[dd * 64 + tq];
    const float4 zv = *(const float4*)&Zs[dd * 64 + e0];
    const float qa[4] = {qv.x, qv.y, qv.z, qv.w};
    const float za[4] = {zv.x, zv.y, zv.z, zv.w};
    #pragma unroll
    for (int i = 0; i < 4; ++i)
      #pragma unroll
      for (int j = 0; j < 4; ++j)
        zt[i][j] = fmaf(qa[i], za[j], zt[i][j]);
  }
  #pragma unroll
  for (int i = 0; i < 4; ++i) {
    const float gt = Gv[tq + i];
    float4 res;
    res.x = fmaf(gt, zt[i][0], o[i][0]);
    res.y = fmaf(gt, zt[i][1], o[i][1]);
    res.z = fmaf(gt, zt[i][2], o[i][2]);
    res.w = fmaf(gt, zt[i][3], o[i][3]);
    *(float4*)(O + ((size_t)(b * SEQ + cs + tq + i)) * DIMC + h * 64 + e0) = res;
  }
}

// ---------------------------------------------------------------- host
extern "C" void kernel_launch(void* const* d_in, const int* in_sizes, int n_in,
                              void* d_out, int out_size, void* d_ws, size_t ws_size,
                              hipStream_t stream)
{
  const float* x  = (const float*)d_in[0];
  const float* Wq = (const float*)d_in[1];
  const float* bq = (const float*)d_in[2];
  const float* Wk = (const float*)d_in[3];
  const float* bk = (const float*)d_in[4];
  const float* Wv = (const float*)d_in[5];
  const float* bv = (const float*)d_in[6];
  const float* Wa = (const float*)d_in[7];
  const float* ba = (const float*)d_in[8];
  const float* Wb = (const float*)d_in[9];
  const float* bb = (const float*)d_in[10];
  const float* cq = (const float*)d_in[11];
  const float* ck = (const float*)d_in[12];
  const float* cv = (const float*)d_in[13];
  const float* Wo = (const float*)d_in[14];
  const float* bo = (const float*)d_in[15];
  float* out = (float*)d_out;
  float* ws  = (float*)d_ws;

  const size_t per_b = (size_t)SEQ * DIMC;     // 2,097,152
  const size_t wsz   = (size_t)DIMC * DIMC;    // 1,048,576

  int bc = BATCH;
  while (bc > 1) {
    size_t fl = 4 * (size_t)bc * per_b + (size_t)bc * SEQ * 32 + 128 * 1024 + 128;
    size_t us = 2 * (size_t)bc * per_b + 8 * wsz + 2 * 128 * 1024;
    if (fl * 4 + us * 2 <= ws_size) break;
    bc >>= 1;
  }

  float* P   = ws;
  float* qb  = P  + (size_t)bc * per_b;
  float* kvp = qb + (size_t)bc * per_b;              // packed kv: [bh][t][128], 2*bc*per_b floats
  float* abb = kvp + 2 * (size_t)bc * per_b;
  float* Wab = abb + (size_t)bc * SEQ * 32;
  float* bab = Wab + 128 * 1024;
  unsigned short* xh   = (unsigned short*)(bab + 128);
  unsigned short* xl   = xh  + (size_t)bc * per_b;
  unsigned short* wqh  = xl  + (size_t)bc * per_b;
  unsigned short* wql  = wqh + wsz;
  unsigned short* wkh  = wql + wsz;
  unsigned short* wkl  = wkh + wsz;
  unsigned short* wvh  = wkl + wsz;
  unsigned short* wvl  = wvh + wsz;
  unsigned short* woh  = wvl + wsz;
  unsigned short* wol  = woh + wsz;
  unsigned short* wabh = wol + wsz;
  unsigned short* wabl = wabh + 128 * 1024;

  // scan-phase aliases: Cf -> xh/xl region (dead after gate GEMM); SC -> P (dead
  // after v-conv); O -> the output slice itself (overwritten by final GEMM).
  float* Cf  = (float*)xh;
  float* SCp = P;

  pack_ab_kernel<<<513, 256, 0, stream>>>(Wa, ba, Wb, bb, Wab, bab);
  cvt_split<<<(int)(wsz / 4 + 255) / 256, 256, 0, stream>>>(Wq, wqh, wql, (int)(wsz / 4));
  cvt_split<<<(int)(wsz / 4 + 255) / 256, 256, 0, stream>>>(Wk, wkh, wkl, (int)(wsz / 4));
  cvt_split<<<(int)(wsz / 4 + 255) / 256, 256, 0, stream>>>(Wv, wvh, wvl, (int)(wsz / 4));
  cvt_split<<<(int)(wsz / 4 + 255) / 256, 256, 0, stream>>>(Wo, woh, wol, (int)(wsz / 4));
  cvt_split<<<(128 * 1024 / 4 + 255) / 256, 256, 0, stream>>>(Wab, wabh, wabl, 128 * 1024 / 4);

  for (int b0 = 0; b0 < BATCH; b0 += bc) {
    const float* xb = x + (size_t)b0 * per_b;
    float* outb = out + (size_t)b0 * per_b;
    const int M = bc * SEQ;
    const int n4 = (int)((size_t)bc * per_b / 4);
    const int nbh = bc * NHEAD;
    dim3 gg(M / 128, DIMC / 128);
    dim3 gab(M / 128, 1);

    cvt_split<<<(n4 + 255) / 256, 256, 0, stream>>>(xb, xh, xl, n4);

    gemm_bf16x3<<<gg, 256, 0, stream>>>(xh, xl, wqh, wql, bq, P, DIMC, DIMC, DIMC, 1);
    conv_kernel<<<dim3(M), 256, 0, stream>>>(P, cq, qb, 1, 0);
    gemm_bf16x3<<<gg, 256, 0, stream>>>(xh, xl, wkh, wkl, bk, P, DIMC, DIMC, DIMC, 1);
    conv_kernel<<<dim3(M), 256, 0, stream>>>(P, ck, kvp, 1, 1);
    gemm_bf16x3<<<gg, 256, 0, stream>>>(xh, xl, wvh, wvl, bv, P, DIMC, DIMC, DIMC, 1);
    conv_kernel<<<dim3(M), 256, 0, stream>>>(P, cv, kvp, 0, 2);
    gemm_bf16x3<<<gab, 256, 0, stream>>>(xh, xl, wabh, wabl, bab, abb, DIMC, 32, 32, 2);
    // pass 1: coef + checkpoints (serial, 1 gll16/pair, LDS-buffered coef)
    scan2_kernel<<<dim3(nbh, 8), 64, 0, stream>>>(kvp, abb, Cf, SCp);
    // pass 2: recompute outputs in parallel -> out slice (scratch; final GEMM overwrites)
    outp_kernel<<<dim3(SEQ / 64, nbh), 256, 0, stream>>>(qb, kvp, Cf, SCp, abb, outb);
    cvt_split<<<(n4 + 255) / 256, 256, 0, stream>>>(outb, xh, xl, n4);
    gemm_bf16x3<<<gg, 256, 0, stream>>>(xh, xl, woh, wol, bo, outb, DIMC, DIMC, DIMC, 0);
  }
}